// Round 2
// baseline (166.785 us; speedup 1.0000x reference)
//
#include <hip/hip_runtime.h>
#include <cstdint>
#include <cstddef>

#define NB 32768      // batch rows
#define KI 512        // input dim
#define NE 8          // experts
#define NX 128        // expert output dim
#define NT 2          // tasks
#define NWD 64        // tower hidden width
#define BM 64         // rows per block
#define THREADS 256
#define SMEM_BYTES 65536

// workspace layout (ushort elements)
#define W2_ELEMS (NE * KI * NX)          // 524288 bf16 (1 MiB)
#define G2_OFF   W2_ELEMS
#define G2_ELEMS (64 * 16 * 8)           // 8192 bf16 (16 KiB)
#define T2_OFF   (G2_OFF + G2_ELEMS)
#define T2_ELEMS (NT * 16 * 64 * 8)      // 16384 bf16 (32 KiB)
#define WS_NEED  ((size_t)(W2_ELEMS + G2_ELEMS + T2_ELEMS) * 2)

typedef __attribute__((ext_vector_type(8))) short bf16x8;
typedef __attribute__((ext_vector_type(4))) float f32x4;

__device__ __forceinline__ unsigned short f2bf(float f) {
  union { float f; unsigned u; } v; v.f = f;
  return (unsigned short)((v.u + 0x7fffu + ((v.u >> 16) & 1u)) >> 16);
}

// Repack We f32 [E][I][X] -> bf16 W2 fragment order: frag(e,kblk,col)[j] = We[e][kblk*8+j][col]
__global__ __launch_bounds__(256) void repack_we_kernel(const float* __restrict__ We,
                                                        unsigned short* __restrict__ ws) {
  int tid = blockIdx.x * 256 + threadIdx.x;  // 65536 frags
  int col  = tid & (NX - 1);
  int kblk = (tid >> 7) & 63;
  int e    = tid >> 13;
  const float* src = We + ((size_t)e * KI + (size_t)kblk * 8) * NX + col;
  bf16x8 v;
#pragma unroll
  for (int j = 0; j < 8; ++j) v[j] = (short)f2bf(src[(size_t)j * NX]);
  *(bf16x8*)(ws + (size_t)tid * 8) = v;
}

// Repack gates [T][I][E] and tW1 [T][X][W] into fragment order.
__global__ __launch_bounds__(256) void repack_aux_kernel(const float* __restrict__ gates,
                                                         const float* __restrict__ tW1,
                                                         unsigned short* __restrict__ ws) {
  int tid = threadIdx.x;
  // G2: frag f = kb*16 + col ; col = t*8+e ; value[j] = gates[t][kb*8+j][e]
#pragma unroll
  for (int i = 0; i < 4; ++i) {
    int f = i * 256 + tid;             // 1024 frags
    int kb = f >> 4, col = f & 15;
    int t = col >> 3, e = col & 7;
    const float* src = gates + (size_t)t * (KI * NE) + (size_t)(kb * 8) * NE + e;
    bf16x8 v;
#pragma unroll
    for (int j = 0; j < 8; ++j) v[j] = (short)f2bf(src[(size_t)j * NE]);
    *(bf16x8*)(ws + G2_OFF + (size_t)f * 8) = v;
  }
  // T2: frag f = (t*16+kb)*64 + col ; value[j] = tW1[t][kb*8+j][col]
#pragma unroll
  for (int i = 0; i < 8; ++i) {
    int f = i * 256 + tid;             // 2048 frags
    int t = f >> 10, kb = (f >> 6) & 15, col = f & 63;
    const float* src = tW1 + (size_t)t * (NX * NWD) + (size_t)(kb * 8) * NWD + col;
    bf16x8 v;
#pragma unroll
    for (int j = 0; j < 8; ++j) v[j] = (short)f2bf(src[(size_t)j * NWD]);
    *(bf16x8*)(ws + T2_OFF + (size_t)f * 8) = v;
  }
}

template <bool USE_WS>
__global__ __launch_bounds__(THREADS, 2)
void moe_fused_kernel(const float* __restrict__ x, const float* __restrict__ We,
                      const float* __restrict__ be, const float* __restrict__ gates,
                      const float* __restrict__ tW1, const float* __restrict__ tb1,
                      const float* __restrict__ tW2, const float* __restrict__ tb2,
                      const unsigned short* __restrict__ ws, float* __restrict__ out) {
  extern __shared__ char smem[];
  // LDS: x tile [64 rows][512 k] bf16, row stride 1024B, 16B XOR-swizzle per row. 64 KiB.
  // After expert loop, [0,32768) reused as shared tile [t][64][128] bf16 (row stride 256B).
  const int tid  = threadIdx.x;
  const int lane = tid & 63;
  const int wid  = tid >> 6;       // 4 waves
  const int l15  = lane & 15;
  const int lhi  = lane >> 4;      // 0..3
  const int wr   = wid >> 1;       // row group (32 rows)
  const int wc   = wid & 1;        // col group (64 cols)
  const int row0 = blockIdx.x * BM;

  // ---------- stage x (fully coalesced), one barrier ----------
  {
    const float4* xs4 = (const float4*)(x + (size_t)row0 * KI);
#pragma unroll
    for (int c = 0; c < 16; ++c) {
      int i = c * 256 + tid;                 // f8-group index, 4096 total
      float4 a0 = xs4[(size_t)i * 2];
      float4 a1 = xs4[(size_t)i * 2 + 1];
      bf16x8 v;
      v[0] = (short)f2bf(a0.x); v[1] = (short)f2bf(a0.y);
      v[2] = (short)f2bf(a0.z); v[3] = (short)f2bf(a0.w);
      v[4] = (short)f2bf(a1.x); v[5] = (short)f2bf(a1.y);
      v[6] = (short)f2bf(a1.z); v[7] = (short)f2bf(a1.w);
      int row = i >> 6;
      int kb  = (i & 63) * 16;
      *(bf16x8*)(smem + row * 1024 + (kb ^ ((row & 7) << 4))) = v;
    }
  }
  __syncthreads();

  // ---------- fragment loaders ----------
  auto loadBfrag = [&](int e, int kblk, int cf) -> bf16x8 {   // kblk in [0,64)
    if constexpr (USE_WS) {
      return *(const bf16x8*)(ws + ((size_t)(e * 64 + kblk) * NX + wc * 64 + cf * 16 + l15) * 8);
    } else {
      const float* src = We + ((size_t)e * KI + (size_t)kblk * 8) * NX + wc * 64 + cf * 16 + l15;
      bf16x8 v;
#pragma unroll
      for (int j = 0; j < 8; ++j) v[j] = (short)f2bf(src[(size_t)j * NX]);
      return v;
    }
  };
  auto loadGfrag = [&](int kb) -> bf16x8 {                    // kb in [0,64)
    if constexpr (USE_WS) {
      return *(const bf16x8*)(ws + G2_OFF + ((size_t)kb * 16 + l15) * 8);
    } else {
      int t = l15 >> 3, e = l15 & 7;
      const float* src = gates + (size_t)t * (KI * NE) + (size_t)(kb * 8) * NE + e;
      bf16x8 v;
#pragma unroll
      for (int j = 0; j < 8; ++j) v[j] = (short)f2bf(src[(size_t)j * NE]);
      return v;
    }
  };
  auto loadTfrag = [&](int t, int kb, int cf) -> bf16x8 {     // kb in [0,16)
    if constexpr (USE_WS) {
      return *(const bf16x8*)(ws + T2_OFF + ((size_t)(t * 16 + kb) * 64 + cf * 16 + l15) * 8);
    } else {
      const float* src = tW1 + (size_t)t * (NX * NWD) + (size_t)(kb * 8) * NWD + cf * 16 + l15;
      bf16x8 v;
#pragma unroll
      for (int j = 0; j < 8; ++j) v[j] = (short)f2bf(src[(size_t)j * NWD]);
      return v;
    }
  };

  // A-fragment: wave rows wr*32 + rf*16 + l15 ; swizzle nibble identical for rf=0/1 (+16 rows)
  const int arow = wr * 32 + l15;
  char* ab0 = smem + arow * 1024;
  char* ab1 = smem + (arow + 16) * 1024;
  const int asw = (arow & 7) << 4;
  auto loadA = [&](int kk, int ks, int rf) -> bf16x8 {
    int byte = (kk * 128 + ks * 64 + lhi * 16) ^ asw;
    return *(const bf16x8*)((rf ? ab1 : ab0) + byte);
  };

  // ---------- accumulators ----------
  f32x4 acc[2][4];
  f32x4 shacc[NT][2][4];
  f32x4 gacc[2];
#pragma unroll
  for (int t = 0; t < NT; ++t)
#pragma unroll
    for (int rf = 0; rf < 2; ++rf)
#pragma unroll
      for (int cf = 0; cf < 4; ++cf) shacc[t][rf][cf] = (f32x4){0.f, 0.f, 0.f, 0.f};
  gacc[0] = (f32x4){0.f, 0.f, 0.f, 0.f};
  gacc[1] = (f32x4){0.f, 0.f, 0.f, 0.f};

  bf16x8 b0[8], b1[8];
  auto loadBset = [&](bf16x8(&dst)[8], int e, int kk) {
#pragma unroll
    for (int ks = 0; ks < 2; ++ks)
#pragma unroll
      for (int cf = 0; cf < 4; ++cf)
        dst[ks * 4 + cf] = loadBfrag(e, kk * 8 + ks * 4 + lhi, cf);
  };

  // prefetch expert0/chunk0 B, then compute g (32 MFMAs) while it lands
  loadBset(b0, 0, 0);
#pragma unroll
  for (int gks = 0; gks < 16; ++gks) {   // K-slice of 32
    bf16x8 gb = loadGfrag(gks * 4 + lhi);
    gacc[0] = __builtin_amdgcn_mfma_f32_16x16x32_bf16(loadA(gks >> 1, gks & 1, 0), gb, gacc[0], 0, 0, 0);
    gacc[1] = __builtin_amdgcn_mfma_f32_16x16x32_bf16(loadA(gks >> 1, gks & 1, 1), gb, gacc[1], 0, 0, 0);
  }

  // one K-chunk (64 k): prefetch next B set, 16 MFMAs with current. No barriers.
  auto chunk = [&](bf16x8(&cur)[8], bf16x8(&nxt)[8], int e, int kk) {
    const int ne_ = (kk == 7) ? ((e + 1) & 7) : e;   // wrap keeps prefetch in-bounds
    const int nk  = (kk == 7) ? 0 : kk + 1;
    loadBset(nxt, ne_, nk);
#pragma unroll
    for (int ks = 0; ks < 2; ++ks) {
      bf16x8 a0v = loadA(kk, ks, 0);
      bf16x8 a1v = loadA(kk, ks, 1);
#pragma unroll
      for (int cf = 0; cf < 4; ++cf) {
        acc[0][cf] = __builtin_amdgcn_mfma_f32_16x16x32_bf16(a0v, cur[ks * 4 + cf], acc[0][cf], 0, 0, 0);
        acc[1][cf] = __builtin_amdgcn_mfma_f32_16x16x32_bf16(a1v, cur[ks * 4 + cf], acc[1][cf], 0, 0, 0);
      }
    }
  };

  auto epilogue = [&](int e) {
#pragma unroll
    for (int rf = 0; rf < 2; ++rf) {
      float gv0[4], gv1[4];
#pragma unroll
      for (int r = 0; r < 4; ++r) {
        gv0[r] = __shfl(gacc[rf][r], (lane & 48) | e, 64);
        gv1[r] = __shfl(gacc[rf][r], (lane & 48) | (8 + e), 64);
      }
#pragma unroll
      for (int cf = 0; cf < 4; ++cf) {
        const float bev = be[e * NX + wc * 64 + cf * 16 + l15];
#pragma unroll
        for (int r = 0; r < 4; ++r) {
          float ex = fmaxf(acc[rf][cf][r] + bev, 0.f);
          shacc[0][rf][cf][r] += gv0[r] * ex;
          shacc[1][rf][cf][r] += gv1[r] * ex;
        }
      }
    }
  };

  for (int e = 0; e < NE; ++e) {
#pragma unroll
    for (int rf = 0; rf < 2; ++rf)
#pragma unroll
      for (int cf = 0; cf < 4; ++cf) acc[rf][cf] = (f32x4){0.f, 0.f, 0.f, 0.f};
    chunk(b0, b1, e, 0); chunk(b1, b0, e, 1);
    chunk(b0, b1, e, 2); chunk(b1, b0, e, 3);
    chunk(b0, b1, e, 4); chunk(b1, b0, e, 5);
    chunk(b0, b1, e, 6); chunk(b1, b0, e, 7);
    epilogue(e);
  }

  // ---------- tower ----------
  __syncthreads();   // everyone done reading x region
#pragma unroll
  for (int t = 0; t < NT; ++t)
#pragma unroll
    for (int rf = 0; rf < 2; ++rf)
#pragma unroll
      for (int cf = 0; cf < 4; ++cf)
#pragma unroll
        for (int r = 0; r < 4; ++r) {
          int row = wr * 32 + rf * 16 + lhi * 4 + r;
          int col = wc * 64 + cf * 16 + l15;
          *(unsigned short*)(smem + t * 16384 + row * 256 + ((col * 2) ^ ((row & 7) << 4))) =
              f2bf(shacc[t][rf][cf][r]);
        }
  __syncthreads();

  const int trow = wid * 16 + l15;
  const char* tbase = smem + trow * 256;
  const int tsw = (trow & 7) << 4;
#pragma unroll
  for (int t = 0; t < NT; ++t) {
    f32x4 hacc[4];
#pragma unroll
    for (int cf = 0; cf < 4; ++cf) hacc[cf] = (f32x4){0.f, 0.f, 0.f, 0.f};
#pragma unroll
    for (int ks = 0; ks < 4; ++ks) {
      bf16x8 a = *(const bf16x8*)(tbase + t * 16384 + ((ks * 64 + lhi * 16) ^ tsw));
#pragma unroll
      for (int cf = 0; cf < 4; ++cf)
        hacc[cf] = __builtin_amdgcn_mfma_f32_16x16x32_bf16(a, loadTfrag(t, ks * 4 + lhi, cf), hacc[cf], 0, 0, 0);
    }
    float p[4] = {0.f, 0.f, 0.f, 0.f};
#pragma unroll
    for (int cf = 0; cf < 4; ++cf) {
      int col = cf * 16 + l15;
      const float b1v = tb1[t * NWD + col];
      const float w2v = tW2[t * NWD + col];
#pragma unroll
      for (int r = 0; r < 4; ++r) p[r] += fmaxf(hacc[cf][r] + b1v, 0.f) * w2v;
    }
#pragma unroll
    for (int r = 0; r < 4; ++r) {
      p[r] += __shfl_xor(p[r], 1, 64);
      p[r] += __shfl_xor(p[r], 2, 64);
      p[r] += __shfl_xor(p[r], 4, 64);
      p[r] += __shfl_xor(p[r], 8, 64);
    }
    if (l15 == 0) {
      const float b2 = tb2[t];
      float4 o;
      o.x = p[0] + b2; o.y = p[1] + b2; o.z = p[2] + b2; o.w = p[3] + b2;
      *(float4*)(out + (size_t)t * NB + row0 + wid * 16 + lhi * 4) = o;
    }
  }
}

extern "C" void kernel_launch(void* const* d_in, const int* in_sizes, int n_in,
                              void* d_out, int out_size, void* d_ws, size_t ws_size,
                              hipStream_t stream) {
  const float* x     = (const float*)d_in[0];
  const float* We    = (const float*)d_in[1];
  const float* be    = (const float*)d_in[2];
  const float* gates = (const float*)d_in[3];
  const float* tW1   = (const float*)d_in[4];
  const float* tb1   = (const float*)d_in[5];
  const float* tW2   = (const float*)d_in[6];
  const float* tb2   = (const float*)d_in[7];
  float* out = (float*)d_out;

  const bool use_ws = (d_ws != nullptr) && (ws_size >= WS_NEED);
  const int nblk = NB / BM;  // 512

  if (use_ws) {
    unsigned short* ws = (unsigned short*)d_ws;
    hipFuncSetAttribute(reinterpret_cast<const void*>(moe_fused_kernel<true>),
                        hipFuncAttributeMaxDynamicSharedMemorySize, SMEM_BYTES);
    repack_we_kernel<<<(W2_ELEMS / 8) / 256, 256, 0, stream>>>(We, ws);
    repack_aux_kernel<<<1, 256, 0, stream>>>(gates, tW1, ws);
    moe_fused_kernel<true><<<nblk, THREADS, SMEM_BYTES, stream>>>(
        x, We, be, gates, tW1, tb1, tW2, tb2, ws, out);
  } else {
    hipFuncSetAttribute(reinterpret_cast<const void*>(moe_fused_kernel<false>),
                        hipFuncAttributeMaxDynamicSharedMemorySize, SMEM_BYTES);
    moe_fused_kernel<false><<<nblk, THREADS, SMEM_BYTES, stream>>>(
        x, We, be, gates, tW1, tb1, tW2, tb2, nullptr, out);
  }
}

// Round 3
// 70.143 us; speedup vs baseline: 2.3778x; 2.3778x over previous
//
#include <hip/hip_runtime.h>
#include <cstdint>
#include <cstddef>

#define NB 32768      // batch rows
#define KI 512        // input dim
#define NE 8          // experts
#define NX 128        // expert output dim
#define NT 2          // tasks
#define NWD 64        // tower hidden width
#define BM 128        // rows per block
#define THREADS 512
#define SMEM_BYTES 163840   /* 128KB x tile + 2x16KB W double buffer */

// workspace layout (ushort elements)
#define W2_ELEMS (NE * KI * NX)          // 524288 bf16 (1 MiB)
#define G2_OFF   W2_ELEMS
#define G2_ELEMS (64 * 16 * 8)           // 8192 bf16 (16 KiB)
#define T2_OFF   (G2_OFF + G2_ELEMS)
#define T2_ELEMS (NT * 16 * 64 * 8)      // 16384 bf16 (32 KiB)
#define WS_NEED  ((size_t)(W2_ELEMS + G2_ELEMS + T2_ELEMS) * 2)

typedef __attribute__((ext_vector_type(8))) short bf16x8;
typedef __attribute__((ext_vector_type(4))) float f32x4;

__device__ __forceinline__ unsigned short f2bf(float f) {
  union { float f; unsigned u; } v; v.f = f;
  return (unsigned short)((v.u + 0x7fffu + ((v.u >> 16) & 1u)) >> 16);
}

#define AS1(p) ((const __attribute__((address_space(1))) void*)(uintptr_t)(p))
#define AS3(p) ((__attribute__((address_space(3))) void*)(uintptr_t)(p))
#define VMCNT2() asm volatile("s_waitcnt vmcnt(2)" ::: "memory")
#define BAR()    __builtin_amdgcn_s_barrier()

// Repack We f32 [E][I][X] -> bf16 fragment order: frag(e,kblk,col)[j] = We[e][kblk*8+j][col]
__global__ __launch_bounds__(256) void repack_we_kernel(const float* __restrict__ We,
                                                        unsigned short* __restrict__ ws) {
  int tid = blockIdx.x * 256 + threadIdx.x;  // 65536 frags
  int col  = tid & (NX - 1);
  int kblk = (tid >> 7) & 63;
  int e    = tid >> 13;
  const float* src = We + ((size_t)e * KI + (size_t)kblk * 8) * NX + col;
  bf16x8 v;
#pragma unroll
  for (int j = 0; j < 8; ++j) v[j] = (short)f2bf(src[(size_t)j * NX]);
  *(bf16x8*)(ws + (size_t)tid * 8) = v;
}

// Repack gates [T][I][E] and tW1 [T][X][W] into fragment order.
__global__ __launch_bounds__(256) void repack_aux_kernel(const float* __restrict__ gates,
                                                         const float* __restrict__ tW1,
                                                         unsigned short* __restrict__ ws) {
  int tid = threadIdx.x;
#pragma unroll
  for (int i = 0; i < 4; ++i) {
    int f = i * 256 + tid;             // 1024 frags: kb*16 + (t*8+e)
    int kb = f >> 4, col = f & 15;
    int t = col >> 3, e = col & 7;
    const float* src = gates + (size_t)t * (KI * NE) + (size_t)(kb * 8) * NE + e;
    bf16x8 v;
#pragma unroll
    for (int j = 0; j < 8; ++j) v[j] = (short)f2bf(src[(size_t)j * NE]);
    *(bf16x8*)(ws + G2_OFF + (size_t)f * 8) = v;
  }
#pragma unroll
  for (int i = 0; i < 8; ++i) {
    int f = i * 256 + tid;             // 2048 frags: (t*16+kb)*64 + col
    int t = f >> 10, kb = (f >> 6) & 15, col = f & 63;
    const float* src = tW1 + (size_t)t * (NX * NWD) + (size_t)(kb * 8) * NWD + col;
    bf16x8 v;
#pragma unroll
    for (int j = 0; j < 8; ++j) v[j] = (short)f2bf(src[(size_t)j * NWD]);
    *(bf16x8*)(ws + T2_OFF + (size_t)f * 8) = v;
  }
}

template <bool USE_WS>
__global__ __launch_bounds__(THREADS, 2)
void moe_fused_kernel(const float* __restrict__ x, const float* __restrict__ We,
                      const float* __restrict__ be, const float* __restrict__ gates,
                      const float* __restrict__ tW1, const float* __restrict__ tb1,
                      const float* __restrict__ tW2, const float* __restrict__ tb2,
                      const unsigned short* __restrict__ ws, float* __restrict__ out) {
  extern __shared__ char smem[];
  // LDS: [0,131072) x tile [128 rows][512 k] bf16, row stride 1024B, 16B XOR swizzle/row.
  //      [131072,163840) W double buffer: 2 x 16KB, frag-linear [kbl(8)][col(128)][16B].
  // After expert loop, [0,65536) reused as shared tile [t][128][128] bf16.
  char* wbuf = smem + 131072;

  const int tid  = threadIdx.x;
  const int lane = tid & 63;
  const int wid  = tid >> 6;       // 8 waves; wave owns rows wid*16..+15, all 128 cols
  const int l15  = lane & 15;
  const int lhi  = lane >> 4;      // 0..3
  const int row0 = blockIdx.x * BM;

  // ---------- stage x upfront (fully coalesced), one full barrier ----------
  {
    const float4* xs4 = (const float4*)(x + (size_t)row0 * KI);
#pragma unroll
    for (int c = 0; c < 16; ++c) {
      int i = c * THREADS + tid;             // 8192 groups of 8 floats
      float4 a0 = xs4[(size_t)i * 2];
      float4 a1 = xs4[(size_t)i * 2 + 1];
      bf16x8 v;
      v[0] = (short)f2bf(a0.x); v[1] = (short)f2bf(a0.y);
      v[2] = (short)f2bf(a0.z); v[3] = (short)f2bf(a0.w);
      v[4] = (short)f2bf(a1.x); v[5] = (short)f2bf(a1.y);
      v[6] = (short)f2bf(a1.z); v[7] = (short)f2bf(a1.w);
      int row = i >> 6;
      int kb  = (i & 63) * 16;
      *(bf16x8*)(smem + row * 1024 + (kb ^ ((row & 7) << 4))) = v;
    }
  }
  __syncthreads();

  // ---------- A-fragment reader ----------
  const int arow = wid * 16 + l15;
  char* abase = smem + arow * 1024;
  const int asw = (arow & 7) << 4;
  auto loadA = [&](int kk, int ks) -> bf16x8 {
    return *(const bf16x8*)(abase + ((kk * 128 + ks * 64 + lhi * 16) ^ asw));
  };

  // ---------- W stage (async to LDS) ----------
  auto stage_w = [&](int e, int kk, int b) {
    if constexpr (USE_WS) {
      const char* gbase = (const char*)ws + ((size_t)(e * 64 + kk * 8) * NX) * 16;
      char* lbase = wbuf + b * 16384 + wid * 1024;
      __builtin_amdgcn_global_load_lds(AS1(gbase + (wid * 64 + lane) * 16), AS3(lbase), 16, 0, 0);
      __builtin_amdgcn_global_load_lds(AS1(gbase + 8192 + (wid * 64 + lane) * 16), AS3(lbase + 8192), 16, 0, 0);
    } else {
      const int col = tid & 127;
      const int kb0 = tid >> 7;  // 0..3
#pragma unroll
      for (int h = 0; h < 2; ++h) {
        const int kblk = kb0 + h * 4;
        const float* src = We + ((size_t)e * KI + (size_t)(kk * 64 + kblk * 8)) * NX + col;
        bf16x8 v;
#pragma unroll
        for (int j = 0; j < 8; ++j) v[j] = (short)f2bf(src[(size_t)j * NX]);
        *(bf16x8*)(wbuf + b * 16384 + (kblk * NX + col) * 16) = v;
      }
    }
  };

  // ---------- accumulators ----------
  f32x4 acc[8];
  f32x4 shacc[NT][8];
  f32x4 gacc = {0.f, 0.f, 0.f, 0.f};
#pragma unroll
  for (int t = 0; t < NT; ++t)
#pragma unroll
    for (int cf = 0; cf < 8; ++cf) shacc[t][cf] = (f32x4){0.f, 0.f, 0.f, 0.f};

  // preload be -> registers (keeps main loop free of counted vmem)
  float be_r[NE][8];
#pragma unroll
  for (int e = 0; e < NE; ++e)
#pragma unroll
    for (int cf = 0; cf < 8; ++cf) be_r[e][cf] = be[e * NX + cf * 16 + l15];

  // ---------- prologue: g-gates MFMA while chunk0 W loads fly ----------
  stage_w(0, 0, 0);
  {
#pragma unroll
    for (int gks = 0; gks < 16; ++gks) {
      bf16x8 gb;
      if constexpr (USE_WS) {
        gb = *(const bf16x8*)(ws + G2_OFF + ((size_t)(gks * 4 + lhi) * 16 + l15) * 8);
      } else {
        int t = l15 >> 3, e = l15 & 7;
        const float* src = gates + (size_t)t * (KI * NE) + (size_t)((gks * 4 + lhi) * 8) * NE + e;
#pragma unroll
        for (int j = 0; j < 8; ++j) gb[j] = (short)f2bf(src[(size_t)j * NE]);
      }
      gacc = __builtin_amdgcn_mfma_f32_16x16x32_bf16(loadA(gks >> 1, gks & 1), gb, gacc, 0, 0, 0);
    }
  }

  // ---------- main expert loop: counted-vmcnt double-buffer, no drains ----------
  for (int e = 0; e < NE; ++e) {
#pragma unroll
    for (int cf = 0; cf < 8; ++cf) acc[cf] = (f32x4){0.f, 0.f, 0.f, 0.f};
#pragma unroll
    for (int kk = 0; kk < 8; ++kk) {
      const int ne_ = (kk == 7) ? ((e + 1) & 7) : e;   // wrap keeps body uniform
      const int nk  = (kk + 1) & 7;
      stage_w(ne_, nk, (kk + 1) & 1);
      if constexpr (USE_WS) { VMCNT2(); BAR(); } else { __syncthreads(); }
      // 16 MFMAs on buffer kk&1
#pragma unroll
      for (int ks = 0; ks < 2; ++ks) {
        bf16x8 av = loadA(kk, ks);
        const char* bbase = wbuf + (kk & 1) * 16384 + ((ks * 4 + lhi) * NX + l15) * 16;
#pragma unroll
        for (int cf = 0; cf < 8; ++cf) {
          bf16x8 bfr = *(const bf16x8*)(bbase + cf * 256);
          acc[cf] = __builtin_amdgcn_mfma_f32_16x16x32_bf16(av, bfr, acc[cf], 0, 0, 0);
        }
      }
      if constexpr (USE_WS) { BAR(); } else { __syncthreads(); }
    }
    // epilogue: relu(+be), shared += g*ex  (registers + shfl only)
    {
      float gv0[4], gv1[4];
#pragma unroll
      for (int r = 0; r < 4; ++r) {
        gv0[r] = __shfl(gacc[r], (lane & 48) | e, 64);
        gv1[r] = __shfl(gacc[r], (lane & 48) | (8 + e), 64);
      }
#pragma unroll
      for (int cf = 0; cf < 8; ++cf) {
        const float bev = be_r[e][cf];
#pragma unroll
        for (int r = 0; r < 4; ++r) {
          float ex = fmaxf(acc[cf][r] + bev, 0.f);
          shacc[0][cf][r] += gv0[r] * ex;
          shacc[1][cf][r] += gv1[r] * ex;
        }
      }
    }
  }

  // ---------- tower ----------
  __syncthreads();   // full drain; everyone done with x region & W pipeline
#pragma unroll
  for (int t = 0; t < NT; ++t)
#pragma unroll
    for (int cf = 0; cf < 8; ++cf)
#pragma unroll
      for (int r = 0; r < 4; ++r) {
        const int rr = wid * 16 + lhi * 4 + r;
        const int cc = cf * 16 + l15;
        *(unsigned short*)(smem + t * 32768 + rr * 256 + ((cc * 2) ^ ((rr & 7) << 4))) =
            f2bf(shacc[t][cf][r]);
      }
  __syncthreads();

  const int trow = wid * 16 + l15;
  const char* tbase = smem + trow * 256;
  const int tsw = (trow & 7) << 4;
#pragma unroll
  for (int t = 0; t < NT; ++t) {
    f32x4 hacc[4];
#pragma unroll
    for (int cf = 0; cf < 4; ++cf) hacc[cf] = (f32x4){0.f, 0.f, 0.f, 0.f};
#pragma unroll
    for (int ks = 0; ks < 4; ++ks) {
      bf16x8 a = *(const bf16x8*)(tbase + t * 32768 + ((ks * 64 + lhi * 16) ^ tsw));
#pragma unroll
      for (int cf = 0; cf < 4; ++cf) {
        bf16x8 bv;
        if constexpr (USE_WS) {
          bv = *(const bf16x8*)(ws + T2_OFF + ((size_t)(t * 16 + ks * 4 + lhi) * 64 + cf * 16 + l15) * 8);
        } else {
          const float* src = tW1 + (size_t)t * (NX * NWD) + (size_t)((ks * 4 + lhi) * 8) * NWD + cf * 16 + l15;
#pragma unroll
          for (int j = 0; j < 8; ++j) bv[j] = (short)f2bf(src[(size_t)j * NWD]);
        }
        hacc[cf] = __builtin_amdgcn_mfma_f32_16x16x32_bf16(a, bv, hacc[cf], 0, 0, 0);
      }
    }
    float p[4] = {0.f, 0.f, 0.f, 0.f};
#pragma unroll
    for (int cf = 0; cf < 4; ++cf) {
      int col = cf * 16 + l15;
      const float b1v = tb1[t * NWD + col];
      const float w2v = tW2[t * NWD + col];
#pragma unroll
      for (int r = 0; r < 4; ++r) p[r] += fmaxf(hacc[cf][r] + b1v, 0.f) * w2v;
    }
#pragma unroll
    for (int r = 0; r < 4; ++r) {
      p[r] += __shfl_xor(p[r], 1, 64);
      p[r] += __shfl_xor(p[r], 2, 64);
      p[r] += __shfl_xor(p[r], 4, 64);
      p[r] += __shfl_xor(p[r], 8, 64);
    }
    if (l15 == 0) {
      const float b2 = tb2[t];
      float4 o;
      o.x = p[0] + b2; o.y = p[1] + b2; o.z = p[2] + b2; o.w = p[3] + b2;
      *(float4*)(out + (size_t)t * NB + row0 + wid * 16 + lhi * 4) = o;
    }
  }
}

extern "C" void kernel_launch(void* const* d_in, const int* in_sizes, int n_in,
                              void* d_out, int out_size, void* d_ws, size_t ws_size,
                              hipStream_t stream) {
  const float* x     = (const float*)d_in[0];
  const float* We    = (const float*)d_in[1];
  const float* be    = (const float*)d_in[2];
  const float* gates = (const float*)d_in[3];
  const float* tW1   = (const float*)d_in[4];
  const float* tb1   = (const float*)d_in[5];
  const float* tW2   = (const float*)d_in[6];
  const float* tb2   = (const float*)d_in[7];
  float* out = (float*)d_out;

  const bool use_ws = (d_ws != nullptr) && (ws_size >= WS_NEED);
  const int nblk = NB / BM;  // 256

  if (use_ws) {
    unsigned short* ws = (unsigned short*)d_ws;
    hipFuncSetAttribute(reinterpret_cast<const void*>(moe_fused_kernel<true>),
                        hipFuncAttributeMaxDynamicSharedMemorySize, SMEM_BYTES);
    repack_we_kernel<<<(W2_ELEMS / 8) / 256, 256, 0, stream>>>(We, ws);
    repack_aux_kernel<<<1, 256, 0, stream>>>(gates, tW1, ws);
    moe_fused_kernel<true><<<nblk, THREADS, SMEM_BYTES, stream>>>(
        x, We, be, gates, tW1, tb1, tW2, tb2, ws, out);
  } else {
    hipFuncSetAttribute(reinterpret_cast<const void*>(moe_fused_kernel<false>),
                        hipFuncAttributeMaxDynamicSharedMemorySize, SMEM_BYTES);
    moe_fused_kernel<false><<<nblk, THREADS, SMEM_BYTES, stream>>>(
        x, We, be, gates, tW1, tb1, tW2, tb2, nullptr, out);
  }
}